// Round 1
// baseline (83.124 us; speedup 1.0000x reference)
//
#include <hip/hip_runtime.h>
#include <hip/hip_bf16.h>

#define N_IN 4096
#define N_OUT 14336
#define TOPK 1228            // int(4096 * 0.3)

// ---------------------------------------------------------------------------
// Kernel A: find the TOPK-th largest |x| via 4-pass radix select on the
// positive-float bit pattern (order-preserving), tie-break by lowest index
// (jax.lax.top_k stable semantics), and write x_masked to workspace.
// Single block, 1024 threads.
// ---------------------------------------------------------------------------
__global__ __launch_bounds__(1024) void topk_mask_kernel(
    const float* __restrict__ x, float* __restrict__ x_masked) {
  __shared__ unsigned int s_abs[N_IN];                  // 16 KB
  __shared__ unsigned int s_hist[256];
  __shared__ unsigned int s_prefix;
  __shared__ unsigned int s_krem;
  __shared__ unsigned long long s_eqsel[N_IN / 64];     // 512 B tie-select mask

  const int tid = threadIdx.x;

  for (int i = tid; i < N_IN; i += 1024)
    s_abs[i] = __float_as_uint(x[i]) & 0x7fffffffu;
  if (tid == 0) { s_prefix = 0u; s_krem = TOPK; }
  __syncthreads();

  // Radix select, MSB byte -> LSB byte.
  for (int pass = 3; pass >= 0; --pass) {
    if (tid < 256) s_hist[tid] = 0u;
    __syncthreads();
    const unsigned int shift = pass * 8;
    const unsigned int maskAbove =
        (pass == 3) ? 0u : (0xFFFFFFFFu << (shift + 8));
    const unsigned int prefix = s_prefix;
    for (int i = tid; i < N_IN; i += 1024) {
      const unsigned int b = s_abs[i];
      if ((b & maskAbove) == prefix)
        atomicAdd(&s_hist[(b >> shift) & 0xFFu], 1u);
    }
    __syncthreads();
    if (tid == 0) {
      unsigned int krem = s_krem;
      unsigned int pfx = s_prefix;
      for (int b = 255; b >= 0; --b) {
        const unsigned int c = s_hist[b];
        if (c >= krem) { pfx |= ((unsigned int)b) << shift; break; }
        krem -= c;
      }
      s_prefix = pfx;
      s_krem = krem;
    }
    __syncthreads();
  }

  const unsigned int t_abs = s_prefix;  // value of TOPK-th largest |x| (bits)
  const unsigned int need = s_krem;     // # of ==t_abs elems to take (>=1)

  // Wave 0 enumerates equal-to-threshold elements in index order.
  if (tid < 64) {
    unsigned int running = 0;
    for (int c = 0; c < N_IN / 64; ++c) {
      const int i = c * 64 + tid;
      const bool eq = (s_abs[i] == t_abs);
      const unsigned long long m = __ballot(eq);
      const unsigned long long below = m & ((1ull << tid) - 1ull);
      const bool sel = eq && (running + (unsigned int)__popcll(below) < need);
      const unsigned long long selmask = __ballot(sel);
      if (tid == 0) s_eqsel[c] = selmask;
      running += (unsigned int)__popcll(m);
    }
  }
  __syncthreads();

  for (int i = tid; i < N_IN; i += 1024) {
    const unsigned int b = s_abs[i];
    const bool sel = (b > t_abs) || (((s_eqsel[i >> 6] >> (i & 63)) & 1ull) != 0ull);
    x_masked[i] = sel ? x[i] : 0.0f;
  }
}

// ---------------------------------------------------------------------------
// Kernel B: out[o] = dot(x_masked, W[o,:]) + bias[o].
// 256 threads = 4 waves per block, one output row per wave.
// W streamed as coalesced float4 (1 KB / wave / instruction).
// ---------------------------------------------------------------------------
__global__ __launch_bounds__(256) void masked_matvec_kernel(
    const float* __restrict__ xm, const float* __restrict__ W,
    const float* __restrict__ bias, float* __restrict__ out) {
  __shared__ float s_x[N_IN];  // 16 KB

  const int tid = threadIdx.x;
  for (int i = tid; i < N_IN; i += 256) s_x[i] = xm[i];
  __syncthreads();

  const int wave = tid >> 6;
  const int lane = tid & 63;
  const int row = blockIdx.x * 4 + wave;
  const float* wr = W + (size_t)row * N_IN;

  float acc = 0.0f;
#pragma unroll
  for (int it = 0; it < N_IN / 256; ++it) {  // 16 iterations
    const int base = it * 256 + lane * 4;
    const float4 w = *reinterpret_cast<const float4*>(wr + base);
    const float4 xv = *reinterpret_cast<const float4*>(&s_x[base]);
    acc += w.x * xv.x + w.y * xv.y + w.z * xv.z + w.w * xv.w;
  }

#pragma unroll
  for (int off = 32; off >= 1; off >>= 1) acc += __shfl_down(acc, off, 64);

  if (lane == 0) out[row] = acc + bias[row];
}

extern "C" void kernel_launch(void* const* d_in, const int* in_sizes, int n_in,
                              void* d_out, int out_size, void* d_ws,
                              size_t ws_size, hipStream_t stream) {
  const float* x    = (const float*)d_in[0];   // (1,1,4096) f32
  const float* W    = (const float*)d_in[1];   // (14336,4096) f32
  const float* bias = (const float*)d_in[2];   // (14336,) f32
  float* out = (float*)d_out;                  // (1,1,14336) f32
  float* xm  = (float*)d_ws;                   // 4096 f32 scratch

  topk_mask_kernel<<<1, 1024, 0, stream>>>(x, xm);
  masked_matvec_kernel<<<N_OUT / 4, 256, 0, stream>>>(xm, W, bias, out);
}

// Round 2
// 58.133 us; speedup vs baseline: 1.4299x; 1.4299x over previous
//
#include <hip/hip_runtime.h>
#include <hip/hip_bf16.h>

#define N_IN 4096
#define N_OUT 14336
#define TOPK 1228            // int(4096 * 0.3)

// ---------------------------------------------------------------------------
// Kernel A: threshold = TOPK-th largest |x| via 4-pass radix select on the
// positive-float bit pattern (order-preserving). Fully parallel:
//   - ballot-aggregated LDS histogram (one atomic per distinct bucket/wave)
//   - 256-wide reversed Hillis-Steele scan replaces the serial bucket walk
//   - parallel tie enumeration (lowest-index-first, jax.lax.top_k stable)
// Writes x_masked (x with non-topk entries zeroed) to workspace.
// Single block, 1024 threads.
// ---------------------------------------------------------------------------
__global__ __launch_bounds__(1024) void topk_mask_kernel(
    const float* __restrict__ x, float* __restrict__ x_masked) {
  __shared__ unsigned int s_abs[N_IN];                  // 16 KB
  __shared__ unsigned int s_hist[256];
  __shared__ unsigned int s_scan[256];
  __shared__ unsigned int s_prefix;
  __shared__ unsigned int s_krem;
  __shared__ unsigned long long s_cmask[N_IN / 64];     // per-chunk eq masks
  __shared__ unsigned int s_cbase[N_IN / 64];           // exclusive tie ranks

  const int tid = threadIdx.x;
  const int lane = tid & 63;

#pragma unroll
  for (int it = 0; it < N_IN / 1024; ++it) {
    const int i = it * 1024 + tid;
    s_abs[i] = __float_as_uint(x[i]) & 0x7fffffffu;
  }
  if (tid == 0) { s_prefix = 0u; s_krem = TOPK; }
  __syncthreads();

  // Radix select, MSB byte -> LSB byte.
  for (int pass = 3; pass >= 0; --pass) {
    if (tid < 256) s_hist[tid] = 0u;
    __syncthreads();
    const int shift = pass * 8;
    const unsigned int maskAbove =
        (pass == 3) ? 0u : (0xFFFFFFFFu << (shift + 8));
    const unsigned int prefix = s_prefix;
    const unsigned int krem = s_krem;  // snapshot before this pass's update

    // Ballot-aggregated histogram: match same-bucket active lanes in-wave,
    // leader lane does a single atomicAdd of the peer count.
#pragma unroll
    for (int it = 0; it < N_IN / 1024; ++it) {
      const int i = it * 1024 + tid;
      const unsigned int b = s_abs[i];
      const bool active = ((b & maskAbove) == prefix);
      const unsigned int bucket = (b >> shift) & 0xFFu;
      unsigned long long m = __ballot(active);
#pragma unroll
      for (int bit = 0; bit < 8; ++bit) {
        const unsigned long long vote =
            __ballot(active && ((bucket >> bit) & 1u));
        m &= ((bucket >> bit) & 1u) ? vote : ~vote;
      }
      if (active) {
        const int leader = __ffsll((unsigned long long)m) - 1;
        if (lane == leader)
          atomicAdd(&s_hist[bucket], (unsigned int)__popcll(m));
      }
    }
    __syncthreads();

    // Reversed inclusive scan: s_scan[r] = C(255-r) = count of elems with
    // bucket >= (255-r) among actives.
    if (tid < 256) s_scan[tid] = s_hist[255 - tid];
    __syncthreads();
    for (int off = 1; off < 256; off <<= 1) {
      unsigned int v = 0u;
      if (tid < 256 && tid >= off) v = s_scan[tid - off];
      __syncthreads();
      if (tid < 256) s_scan[tid] += v;
      __syncthreads();
    }
    if (tid < 256) {
      const unsigned int t = (unsigned int)tid;  // bucket id
      const unsigned int C = s_scan[255 - t];    // count with bucket >= t
      const unsigned int S = (t == 255u) ? 0u : s_scan[254 - t];  // > t
      if (S < krem && C >= krem) {               // unique winner
        s_prefix = prefix | (t << shift);
        s_krem = krem - S;
      }
    }
    __syncthreads();
  }

  const unsigned int t_abs = s_prefix;  // bits of TOPK-th largest |x|
  const unsigned int need = s_krem;     // # of ==t_abs elems to take (>=1)

  // Parallel tie enumeration: per-64-chunk eq ballot masks ...
#pragma unroll
  for (int it = 0; it < N_IN / 1024; ++it) {
    const int i = it * 1024 + tid;
    const bool eq = (s_abs[i] == t_abs);
    const unsigned long long m = __ballot(eq);
    if (lane == 0) s_cmask[i >> 6] = m;
  }
  __syncthreads();
  // ... then one wave exclusive-scans the 64 chunk counts.
  if (tid < 64) {
    const unsigned int cnt = (unsigned int)__popcll(s_cmask[tid]);
    unsigned int inc = cnt;
#pragma unroll
    for (int off = 1; off < 64; off <<= 1) {
      const unsigned int v = __shfl_up(inc, off, 64);
      if (lane >= off) inc += v;
    }
    s_cbase[tid] = inc - cnt;
  }
  __syncthreads();

#pragma unroll
  for (int it = 0; it < N_IN / 1024; ++it) {
    const int i = it * 1024 + tid;
    const unsigned int b = s_abs[i];
    bool sel = (b > t_abs);
    if (b == t_abs) {
      const unsigned long long below =
          s_cmask[i >> 6] & ((1ull << lane) - 1ull);
      sel = (s_cbase[i >> 6] + (unsigned int)__popcll(below)) < need;
    }
    x_masked[i] = sel ? x[i] : 0.0f;
  }
}

// ---------------------------------------------------------------------------
// Kernel B: out[o] = dot(x_masked, W[o,:]) + bias[o].
// 256 threads = 4 waves per block, one output row per wave.
// W streamed as coalesced float4 (1 KB / wave / instruction).
// ---------------------------------------------------------------------------
__global__ __launch_bounds__(256) void masked_matvec_kernel(
    const float* __restrict__ xm, const float* __restrict__ W,
    const float* __restrict__ bias, float* __restrict__ out) {
  __shared__ float s_x[N_IN];  // 16 KB

  const int tid = threadIdx.x;
  for (int i = tid; i < N_IN; i += 256) s_x[i] = xm[i];
  __syncthreads();

  const int wave = tid >> 6;
  const int lane = tid & 63;
  const int row = blockIdx.x * 4 + wave;
  const float* wr = W + (size_t)row * N_IN;

  float acc = 0.0f;
#pragma unroll
  for (int it = 0; it < N_IN / 256; ++it) {  // 16 iterations
    const int base = it * 256 + lane * 4;
    const float4 w = *reinterpret_cast<const float4*>(wr + base);
    const float4 xv = *reinterpret_cast<const float4*>(&s_x[base]);
    acc += w.x * xv.x + w.y * xv.y + w.z * xv.z + w.w * xv.w;
  }

#pragma unroll
  for (int off = 32; off >= 1; off >>= 1) acc += __shfl_down(acc, off, 64);

  if (lane == 0) out[row] = acc + bias[row];
}

extern "C" void kernel_launch(void* const* d_in, const int* in_sizes, int n_in,
                              void* d_out, int out_size, void* d_ws,
                              size_t ws_size, hipStream_t stream) {
  const float* x    = (const float*)d_in[0];   // (1,1,4096) f32
  const float* W    = (const float*)d_in[1];   // (14336,4096) f32
  const float* bias = (const float*)d_in[2];   // (14336,) f32
  float* out = (float*)d_out;                  // (1,1,14336) f32
  float* xm  = (float*)d_ws;                   // 4096 f32 scratch

  topk_mask_kernel<<<1, 1024, 0, stream>>>(x, xm);
  masked_matvec_kernel<<<N_OUT / 4, 256, 0, stream>>>(xm, W, bias, out);
}